// Round 7
// baseline (115.358 us; speedup 1.0000x reference)
//
#include <hip/hip_runtime.h>
#include <hip/hip_bf16.h>

// AttentionNTKChoiceModel — split-K barrier-free attention version.
// B=32, L=512, D=128, H=8, D0=D2=32.
//
// convert: X[16384,128]f32 -> X2[16384,256]bf16  (cols 0..127 hi, 128..255 lo)
//          Wc[576,256]bf16: rows W1(0..255), W2(256..511), u(512..519), 0-pad
//          u_h = sum_d w[h,d]*W3[h*32+d,:]/sqrt(8)
// proj:    acc = X2 . Wc[diag chunk] + X2 . Wc[chunk+128 mod 256]
//          (diag = hh+ll, shifted = hl+lh -> exact f32 product). 64x64 tile.
//          Epilogue re-splits into per-head Q2/K2 [B,H,L,64]bf16
//          (d 0..31 hi, 32..63 lo; Q pre-scaled 1/sqrt(32)*log2e), Vw[B,H,L]f32.
// attn:    ONE WAVE per (head, 16-q tile, 128-key split). No LDS, no barriers;
//          K/Vw/mask streamed from L2. Online softmax over 2x64-key chunks.
//          Partials (m, lsum, val) -> Pm/Pl/Pv.
// combine: merge 4 key-splits per (head,q) -> vws[B,H,L].
// final:   sum heads, q-mask, 512-wide softmax per batch row.

typedef __attribute__((ext_vector_type(8))) short bf16x8;
typedef __attribute__((ext_vector_type(4))) float f32x4;
typedef __attribute__((ext_vector_type(8))) unsigned short ushort8;
typedef __attribute__((ext_vector_type(4))) unsigned short ushort4v;

#define NEG (-10000.0f)
#define LOG2E 1.4426950408889634f
#define QSCALE (0.17677669529663687f * LOG2E)
#define NEGL (NEG * LOG2E)

__device__ __forceinline__ unsigned short bf16_rn(float x, float* rep) {
  unsigned u = __float_as_uint(x);
  unsigned r = (u + 0x7FFFu + ((u >> 16) & 1u)) >> 16;
  *rep = __uint_as_float(r << 16);
  return (unsigned short)r;
}

// grid 1057 x 256: [0,1024) X-split, [1024,1056) W1/W2-split, 1056 u+pad
__global__ __launch_bounds__(256) void convert_kernel(
    const float* __restrict__ X, const float* __restrict__ W1,
    const float* __restrict__ W2, const float* __restrict__ W3,
    const float* __restrict__ w,
    unsigned short* __restrict__ X2, unsigned short* __restrict__ Wc) {
  const int bx = blockIdx.x, t = threadIdx.x;
  if (bx < 1056) {
    const float* src;
    unsigned short* dst;
    int row, c;
    if (bx < 1024) {
      const size_t flat = (size_t)bx * 2048 + t * 8;
      row = (int)(flat >> 7); c = (int)(flat & 127);
      src = &X[flat];
      dst = &X2[(size_t)row * 256 + c];
    } else {
      const int flat = (bx - 1024) * 2048 + t * 8;
      row = flat >> 7; c = flat & 127;
      src = (row < 256) ? &W1[(size_t)row * 128 + c]
                        : &W2[(size_t)(row - 256) * 128 + c];
      dst = &Wc[(size_t)row * 256 + c];
    }
    float xv[8];
    *(float4*)&xv[0] = *(const float4*)src;
    *(float4*)&xv[4] = *(const float4*)(src + 4);
    ushort8 hi, lo;
#pragma unroll
    for (int i = 0; i < 8; ++i) {
      float hf, lf;
      hi[i] = bf16_rn(xv[i], &hf);
      lo[i] = bf16_rn(xv[i] - hf, &lf);
    }
    *(ushort8*)dst = hi;
    *(ushort8*)(dst + 128) = lo;
  } else {
    __shared__ float uS[8][128];
    if (t < 128) {
#pragma unroll
      for (int h = 0; h < 8; ++h) {
        float acc = 0.f;
#pragma unroll
        for (int d = 0; d < 32; ++d)
          acc += W3[(h * 32 + d) * 128 + t] * w[h * 32 + d];
        uS[h][t] = acc * 0.3535533905932738f;  // 1/sqrt(8)
      }
    }
    __syncthreads();
    {
      const int r = t >> 5, c = (t & 31) * 4;
      float4 v = *(float4*)&uS[r][c];
      float vv[4] = {v.x, v.y, v.z, v.w};
      ushort4v hi, lo;
#pragma unroll
      for (int i = 0; i < 4; ++i) {
        float hf, lf;
        hi[i] = bf16_rn(vv[i], &hf);
        lo[i] = bf16_rn(vv[i] - hf, &lf);
      }
      *(ushort4v*)&Wc[(size_t)(512 + r) * 256 + c] = hi;
      *(ushort4v*)&Wc[(size_t)(512 + r) * 256 + 128 + c] = lo;
    }
    const ushort8 z = {};
    for (int i = t; i < 1792; i += 256)  // zero rows 520..575
      *(ushort8*)&Wc[(size_t)520 * 256 + i * 8] = z;
  }
}

// [16384,576] GEMM, exact 4-term: diag (hh+ll) + shifted (hl+lh).
// Block 256thr (4 waves), tile 64x64, K chunks of 64 over the 256-wide [hi|lo].
__global__ __launch_bounds__(256) void proj_kernel(
    const unsigned short* __restrict__ X2, const unsigned short* __restrict__ Wc,
    unsigned short* __restrict__ Q2, unsigned short* __restrict__ K2,
    float* __restrict__ Vw) {
  // stride 72 ushort = 144B (36 dw, %8==4 -> 2-way max on frag reads)
  __shared__ unsigned short XS[64][72], WSd[64][72], WSx[64][72];
  const int t = threadIdx.x;
  const int row0 = blockIdx.x * 64, col0 = blockIdx.y * 64;
  const int w = t >> 6, lane = t & 63, g = lane >> 4, r16 = lane & 15;
  const int srow = t >> 2, su = (t & 3) * 16;

  f32x4 acc[4];
#pragma unroll
  for (int n = 0; n < 4; ++n) acc[n] = (f32x4){0.f, 0.f, 0.f, 0.f};

  for (int kc = 0; kc < 256; kc += 64) {
    const int kcx = (kc + 128) & 255;
    if (kc) __syncthreads();
    {
      const size_t xo = (size_t)(row0 + srow) * 256 + kc + su;
      const size_t wd = (size_t)(col0 + srow) * 256 + kc + su;
      const size_t wx = (size_t)(col0 + srow) * 256 + kcx + su;
      ushort8 a = *(const ushort8*)&X2[xo];
      ushort8 b = *(const ushort8*)&X2[xo + 8];
      ushort8 c = *(const ushort8*)&Wc[wd];
      ushort8 d = *(const ushort8*)&Wc[wd + 8];
      ushort8 e = *(const ushort8*)&Wc[wx];
      ushort8 f = *(const ushort8*)&Wc[wx + 8];
      *(ushort8*)&XS[srow][su] = a;
      *(ushort8*)&XS[srow][su + 8] = b;
      *(ushort8*)&WSd[srow][su] = c;
      *(ushort8*)&WSd[srow][su + 8] = d;
      *(ushort8*)&WSx[srow][su] = e;
      *(ushort8*)&WSx[srow][su + 8] = f;
    }
    __syncthreads();
#pragma unroll
    for (int ks = 0; ks < 2; ++ks) {
      bf16x8 ah = *(const bf16x8*)&XS[w * 16 + r16][ks * 32 + g * 8];
#pragma unroll
      for (int n = 0; n < 4; ++n) {
        bf16x8 bd = *(const bf16x8*)&WSd[n * 16 + r16][ks * 32 + g * 8];
        bf16x8 bx = *(const bf16x8*)&WSx[n * 16 + r16][ks * 32 + g * 8];
        acc[n] = __builtin_amdgcn_mfma_f32_16x16x32_bf16(ah, bd, acc[n], 0, 0, 0);
        acc[n] = __builtin_amdgcn_mfma_f32_16x16x32_bf16(ah, bx, acc[n], 0, 0, 0);
      }
    }
  }
  // C layout: row = w*16 + g*4 + r, col = col0 + n*16 + r16 (verified r2)
#pragma unroll
  for (int n = 0; n < 4; ++n) {
    const int col = col0 + n * 16 + r16;
#pragma unroll
    for (int r = 0; r < 4; ++r) {
      const int row = row0 + w * 16 + g * 4 + r;
      const int b = row >> 9, l = row & 511;
      const float val = acc[n][r];
      if (col < 256) {
        const float sv = val * QSCALE;
        float hf, lf;
        const unsigned short hb = bf16_rn(sv, &hf);
        const unsigned short lb = bf16_rn(sv - hf, &lf);
        const size_t o = ((size_t)(b * 8 + (col >> 5)) * 512 + l) * 64 + (col & 31);
        Q2[o] = hb; Q2[o + 32] = lb;
      } else if (col < 512) {
        const int c2 = col - 256;
        float hf, lf;
        const unsigned short hb = bf16_rn(val, &hf);
        const unsigned short lb = bf16_rn(val - hf, &lf);
        const size_t o = ((size_t)(b * 8 + (c2 >> 5)) * 512 + l) * 64 + (c2 & 31);
        K2[o] = hb; K2[o + 32] = lb;
      } else if (col < 520) {
        Vw[(size_t)(b * 8 + (col - 512)) * 512 + l] = val;
      }
    }
  }
}

// ONE WAVE per task = (head, 16-q tile, 128-key split). 256thr = 4 tasks/block.
// No LDS, no __syncthreads. grid = 32768/4 = 8192 blocks.
__global__ __launch_bounds__(256) void attn_kernel(
    const unsigned short* __restrict__ Q2, const unsigned short* __restrict__ K2,
    const float* __restrict__ Vw, const int* __restrict__ mask,
    float* __restrict__ Pm, float* __restrict__ Pl, float* __restrict__ Pv) {
  const int lane = threadIdx.x & 63;
  const int g = lane >> 4, r16 = lane & 15;
  const int task = blockIdx.x * 4 + (threadIdx.x >> 6);
  const int ks = task & 3;           // key split 0..3 (128 keys each)
  const int qt = (task >> 2) & 31;   // q tile 0..31 (16 q each)
  const int head = task >> 7;        // 0..255 = b*8+h
  const int b = head >> 3;
  const size_t headoff = (size_t)head * 512;

  const size_t qrow = headoff + qt * 16 + r16;
  const bf16x8 qh = *(const bf16x8*)&Q2[qrow * 64 + g * 8];
  const bf16x8 ql = *(const bf16x8*)&Q2[qrow * 64 + 32 + g * 8];

  float m = -1e30f, lsum = 0.f, val = 0.f;

#pragma unroll
  for (int cc = 0; cc < 2; ++cc) {
    const int key0 = ks * 128 + cc * 64;
    bf16x8 a0[4], a1[4];
    int4 mk4[4];
    float4 vw4[4];
#pragma unroll
    for (int j = 0; j < 4; ++j) {
      const size_t krow = headoff + key0 + j * 16 + r16;
      a0[j] = *(const bf16x8*)&K2[krow * 64 + g * 8];
      a1[j] = *(const bf16x8*)&K2[krow * 64 + 32 + g * 8];
      mk4[j] = *(const int4*)&mask[b * 512 + key0 + j * 16 + g * 4];
      vw4[j] = *(const float4*)&Vw[headoff + key0 + j * 16 + g * 4];
    }
    f32x4 sc[4];
#pragma unroll
    for (int j = 0; j < 4; ++j) {
      f32x4 z = (f32x4){0.f, 0.f, 0.f, 0.f};
      z = __builtin_amdgcn_mfma_f32_16x16x32_bf16(a0[j], qh, z, 0, 0, 0);
      z = __builtin_amdgcn_mfma_f32_16x16x32_bf16(a0[j], ql, z, 0, 0, 0);
      z = __builtin_amdgcn_mfma_f32_16x16x32_bf16(a1[j], qh, z, 0, 0, 0);
      sc[j] = z;
    }
    float sb[4][4];
    float cmax = -1e30f;
#pragma unroll
    for (int j = 0; j < 4; ++j) {
      sb[j][0] = sc[j][0] + (mk4[j].x ? 0.f : NEGL);
      sb[j][1] = sc[j][1] + (mk4[j].y ? 0.f : NEGL);
      sb[j][2] = sc[j][2] + (mk4[j].z ? 0.f : NEGL);
      sb[j][3] = sc[j][3] + (mk4[j].w ? 0.f : NEGL);
#pragma unroll
      for (int r = 0; r < 4; ++r) cmax = fmaxf(cmax, sb[j][r]);
    }
    cmax = fmaxf(cmax, __shfl_xor(cmax, 16));
    cmax = fmaxf(cmax, __shfl_xor(cmax, 32));
    const float mnew = fmaxf(m, cmax);
    const float f = __builtin_amdgcn_exp2f(m - mnew);
    m = mnew;
    float ls = lsum * f, vv = val * f;
#pragma unroll
    for (int j = 0; j < 4; ++j) {
      const float p0 = __builtin_amdgcn_exp2f(sb[j][0] - mnew);
      const float p1 = __builtin_amdgcn_exp2f(sb[j][1] - mnew);
      const float p2 = __builtin_amdgcn_exp2f(sb[j][2] - mnew);
      const float p3 = __builtin_amdgcn_exp2f(sb[j][3] - mnew);
      ls += (p0 + p1) + (p2 + p3);
      vv = fmaf(p0, vw4[j].x, vv);
      vv = fmaf(p1, vw4[j].y, vv);
      vv = fmaf(p2, vw4[j].z, vv);
      vv = fmaf(p3, vw4[j].w, vv);
    }
    lsum = ls; val = vv;
  }
  lsum += __shfl_xor(lsum, 16);
  val  += __shfl_xor(val, 16);
  lsum += __shfl_xor(lsum, 32);
  val  += __shfl_xor(val, 32);
  if (lane < 16) {
    const size_t po = (size_t)task * 16 + r16;
    Pm[po] = m; Pl[po] = lsum; Pv[po] = val;
  }
}

// grid 512 x 256: one thread per (head, q) = 131072
__global__ __launch_bounds__(256) void combine_kernel(
    const float* __restrict__ Pm, const float* __restrict__ Pl,
    const float* __restrict__ Pv, float* __restrict__ vws) {
  const int i = blockIdx.x * 256 + threadIdx.x;
  const int q16 = i & 15, tile = i >> 4;  // tile = head*32 + qt
  float m[4], l[4], v[4];
#pragma unroll
  for (int s = 0; s < 4; ++s) {
    const size_t po = ((size_t)tile * 4 + s) * 16 + q16;
    m[s] = Pm[po]; l[s] = Pl[po]; v[s] = Pv[po];
  }
  const float ms = fmaxf(fmaxf(m[0], m[1]), fmaxf(m[2], m[3]));
  float L = 0.f, V = 0.f;
#pragma unroll
  for (int s = 0; s < 4; ++s) {
    const float f = __builtin_amdgcn_exp2f(m[s] - ms);
    L = fmaf(l[s], f, L);
    V = fmaf(v[s], f, V);
  }
  vws[i] = V / L;  // i == head*512 + qt*16 + q16
}

__global__ __launch_bounds__(512) void final_kernel(
    const float* __restrict__ vws, const int* __restrict__ mask,
    float* __restrict__ out) {
  const int b = blockIdx.x, l = threadIdx.x;  // grid 32, block 512
  __shared__ float redm[8], reds[8];
  float v = 0.f;
#pragma unroll
  for (int h = 0; h < 8; ++h) v += vws[(size_t)(b * 8 + h) * 512 + l];
  if (mask[b * 512 + l] == 0) v = NEG;
  float mx = v;
#pragma unroll
  for (int off = 32; off >= 1; off >>= 1) mx = fmaxf(mx, __shfl_xor(mx, off));
  if ((l & 63) == 0) redm[l >> 6] = mx;
  __syncthreads();
  float M = redm[0];
#pragma unroll
  for (int i = 1; i < 8; ++i) M = fmaxf(M, redm[i]);
  const float e = __expf(v - M);
  float sm = e;
#pragma unroll
  for (int off = 32; off >= 1; off >>= 1) sm += __shfl_xor(sm, off);
  if ((l & 63) == 0) reds[l >> 6] = sm;
  __syncthreads();
  float S = 0.f;
#pragma unroll
  for (int i = 0; i < 8; ++i) S += reds[i];
  out[b * 512 + l] = e / S;
}

extern "C" void kernel_launch(void* const* d_in, const int* in_sizes, int n_in,
                              void* d_out, int out_size, void* d_ws, size_t ws_size,
                              hipStream_t stream) {
  const float* X  = (const float*)d_in[0];
  const int*  mk  = (const int*)d_in[1];
  const float* W1 = (const float*)d_in[2];
  const float* W2 = (const float*)d_in[3];
  const float* W3 = (const float*)d_in[4];
  const float* w  = (const float*)d_in[5];
  float* out = (float*)d_out;

  char* ws = (char*)d_ws;
  unsigned short* X2 = (unsigned short*)ws;                 // 16384*256  = 8 MB
  unsigned short* Wc = X2 + (size_t)16384 * 256;            //   576*256  = 288 KB
  unsigned short* Q2 = Wc + (size_t)576 * 256;              // 32*8*512*64 = 16 MB
  unsigned short* K2 = Q2 + (size_t)32 * 8 * 512 * 64;      // 16 MB
  float* Vw  = (float*)(K2 + (size_t)32 * 8 * 512 * 64);    // 512 KB
  float* vws = Vw + (size_t)32 * 8 * 512;                   // 512 KB
  float* Pm  = vws + (size_t)32 * 8 * 512;                  // 2 MB
  float* Pl  = Pm + (size_t)32768 * 16;                     // 2 MB
  float* Pv  = Pl + (size_t)32768 * 16;                     // 2 MB

  convert_kernel<<<dim3(1057), dim3(256), 0, stream>>>(X, W1, W2, W3, w, X2, Wc);
  proj_kernel<<<dim3(256, 9), dim3(256), 0, stream>>>(X2, Wc, Q2, K2, Vw);
  attn_kernel<<<dim3(8192), dim3(256), 0, stream>>>(Q2, K2, Vw, mk, Pm, Pl, Pv);
  combine_kernel<<<dim3(512), dim3(256), 0, stream>>>(Pm, Pl, Pv, vws);
  final_kernel<<<dim3(32), dim3(512), 0, stream>>>(vws, mk, out);
}

// Round 8
// 72.976 us; speedup vs baseline: 1.5808x; 1.5808x over previous
//
#include <hip/hip_runtime.h>
#include <hip/hip_bf16.h>

// AttentionNTKChoiceModel — r8: coalesced proj stores + L2-friendly grid +
// two-pass (max, then sum) attention softmax.
// B=32, L=512, D=128, H=8, D0=D2=32.
//
// convert: X[16384,128]f32 -> X2[16384,256]bf16  (cols 0..127 hi, 128..255 lo)
//          Wc[576,256]bf16: rows W1(0..255), W2(256..511), u(512..519), 0-pad
//          u_h = sum_d w[h,d]*W3[h*32+d,:]/sqrt(8)
// proj:    grid (9 cols, 256 rows) so the 9 blocks sharing an X2 row-tile are
//          dispatch-adjacent (L2 reuse). acc = X2.Wc[kc] + X2.Wc[kc+128 mod 256]
//          (diag hh+ll + cross hl+lh = exact f32 product). Epilogue: acc ->
//          LDS f32 tile -> coalesced 16B stores into per-head Q2/K2
//          [B,H,L,64]bf16 (d0..31 hi, 32..63 lo; Q pre-scaled 1/sqrt(32)*log2e)
//          and Vw[B,H,L]f32.
// attn:    per (qhalf,h,b): whole 512-key head in LDS (1 barrier). Pass 1:
//          scores^T = K@Q^T (3-term hh+hl+lh), track max only. Pass 2:
//          recompute scores, p = exp2(s - max), accumulate lsum/val. No
//          online rescale chain. -> vws[B,H,L]
// final:   sum heads, q-mask, 512-wide softmax per batch row.

typedef __attribute__((ext_vector_type(8))) short bf16x8;
typedef __attribute__((ext_vector_type(4))) float f32x4;
typedef __attribute__((ext_vector_type(8))) unsigned short ushort8;
typedef __attribute__((ext_vector_type(4))) unsigned short ushort4v;

#define NEG (-10000.0f)
#define LOG2E 1.4426950408889634f
#define QSCALE (0.17677669529663687f * LOG2E)

__device__ __forceinline__ unsigned short bf16_rn(float x, float* rep) {
  unsigned u = __float_as_uint(x);
  unsigned r = (u + 0x7FFFu + ((u >> 16) & 1u)) >> 16;
  *rep = __uint_as_float(r << 16);
  return (unsigned short)r;
}

// grid 1057 x 256: [0,1024) X-split, [1024,1056) W1/W2-split, 1056 u+pad
__global__ __launch_bounds__(256) void convert_kernel(
    const float* __restrict__ X, const float* __restrict__ W1,
    const float* __restrict__ W2, const float* __restrict__ W3,
    const float* __restrict__ w,
    unsigned short* __restrict__ X2, unsigned short* __restrict__ Wc) {
  const int bx = blockIdx.x, t = threadIdx.x;
  if (bx < 1056) {
    const float* src;
    unsigned short* dst;
    int row, c;
    if (bx < 1024) {
      const size_t flat = (size_t)bx * 2048 + t * 8;
      row = (int)(flat >> 7); c = (int)(flat & 127);
      src = &X[flat];
      dst = &X2[(size_t)row * 256 + c];
    } else {
      const int flat = (bx - 1024) * 2048 + t * 8;
      row = flat >> 7; c = flat & 127;
      src = (row < 256) ? &W1[(size_t)row * 128 + c]
                        : &W2[(size_t)(row - 256) * 128 + c];
      dst = &Wc[(size_t)row * 256 + c];
    }
    float xv[8];
    *(float4*)&xv[0] = *(const float4*)src;
    *(float4*)&xv[4] = *(const float4*)(src + 4);
    ushort8 hi, lo;
#pragma unroll
    for (int i = 0; i < 8; ++i) {
      float hf, lf;
      hi[i] = bf16_rn(xv[i], &hf);
      lo[i] = bf16_rn(xv[i] - hf, &lf);
    }
    *(ushort8*)dst = hi;
    *(ushort8*)(dst + 128) = lo;
  } else {
    __shared__ float uS[8][128];
    if (t < 128) {
#pragma unroll
      for (int h = 0; h < 8; ++h) {
        float acc = 0.f;
#pragma unroll
        for (int d = 0; d < 32; ++d)
          acc += W3[(h * 32 + d) * 128 + t] * w[h * 32 + d];
        uS[h][t] = acc * 0.3535533905932738f;  // 1/sqrt(8)
      }
    }
    __syncthreads();
    {
      const int r = t >> 5, c = (t & 31) * 4;
      float4 v = *(float4*)&uS[r][c];
      float vv[4] = {v.x, v.y, v.z, v.w};
      ushort4v hi, lo;
#pragma unroll
      for (int i = 0; i < 4; ++i) {
        float hf, lf;
        hi[i] = bf16_rn(vv[i], &hf);
        lo[i] = bf16_rn(vv[i] - hf, &lf);
      }
      *(ushort4v*)&Wc[(size_t)(512 + r) * 256 + c] = hi;
      *(ushort4v*)&Wc[(size_t)(512 + r) * 256 + 128 + c] = lo;
    }
    const ushort8 z = {};
    for (int i = t; i < 1792; i += 256)  // zero rows 520..575
      *(ushort8*)&Wc[(size_t)520 * 256 + i * 8] = z;
  }
}

// [16384,576] GEMM, exact 4-term. Block 256thr (4 waves), tile 64x64.
// grid (9 cols, 256 rows): adjacent blocks share the X2 row-tile (L2 reuse).
__global__ __launch_bounds__(256) void proj_kernel(
    const unsigned short* __restrict__ X2, const unsigned short* __restrict__ Wc,
    unsigned short* __restrict__ Q2, unsigned short* __restrict__ K2,
    float* __restrict__ Vw) {
  __shared__ unsigned short XS[64][72], WSd[64][72], WSx[64][72];
  __shared__ float SOUT[64][68];
  const int t = threadIdx.x;
  const int row0 = blockIdx.y * 64, col0 = blockIdx.x * 64;
  const int w = t >> 6, lane = t & 63, g = lane >> 4, r16 = lane & 15;
  const int srow = t >> 2, su = (t & 3) * 16;

  f32x4 acc[4];
#pragma unroll
  for (int n = 0; n < 4; ++n) acc[n] = (f32x4){0.f, 0.f, 0.f, 0.f};

  for (int kc = 0; kc < 256; kc += 64) {
    const int kcx = (kc + 128) & 255;
    if (kc) __syncthreads();
    {
      const size_t xo = (size_t)(row0 + srow) * 256 + kc + su;
      const size_t wd = (size_t)(col0 + srow) * 256 + kc + su;
      const size_t wx = (size_t)(col0 + srow) * 256 + kcx + su;
      ushort8 a = *(const ushort8*)&X2[xo];
      ushort8 b = *(const ushort8*)&X2[xo + 8];
      ushort8 c = *(const ushort8*)&Wc[wd];
      ushort8 d = *(const ushort8*)&Wc[wd + 8];
      ushort8 e = *(const ushort8*)&Wc[wx];
      ushort8 f = *(const ushort8*)&Wc[wx + 8];
      *(ushort8*)&XS[srow][su] = a;
      *(ushort8*)&XS[srow][su + 8] = b;
      *(ushort8*)&WSd[srow][su] = c;
      *(ushort8*)&WSd[srow][su + 8] = d;
      *(ushort8*)&WSx[srow][su] = e;
      *(ushort8*)&WSx[srow][su + 8] = f;
    }
    __syncthreads();
#pragma unroll
    for (int ks = 0; ks < 2; ++ks) {
      bf16x8 ah = *(const bf16x8*)&XS[w * 16 + r16][ks * 32 + g * 8];
#pragma unroll
      for (int n = 0; n < 4; ++n) {
        bf16x8 bd = *(const bf16x8*)&WSd[n * 16 + r16][ks * 32 + g * 8];
        bf16x8 bx = *(const bf16x8*)&WSx[n * 16 + r16][ks * 32 + g * 8];
        acc[n] = __builtin_amdgcn_mfma_f32_16x16x32_bf16(ah, bd, acc[n], 0, 0, 0);
        acc[n] = __builtin_amdgcn_mfma_f32_16x16x32_bf16(ah, bx, acc[n], 0, 0, 0);
      }
    }
  }
  // epilogue: acc -> LDS f32 tile -> coalesced 16B stores
  __syncthreads();
#pragma unroll
  for (int n = 0; n < 4; ++n)
#pragma unroll
    for (int r = 0; r < 4; ++r)
      SOUT[w * 16 + g * 4 + r][n * 16 + r16] = acc[n][r];
  __syncthreads();
  {
    const int row = t >> 2, q4 = t & 3;
    const int grow = row0 + row, bb = grow >> 9, l = grow & 511;
    const int gc0 = col0 + q4 * 16;
    float v16[16];
#pragma unroll
    for (int i = 0; i < 4; ++i)
      *(float4*)&v16[i * 4] = *(float4*)&SOUT[row][q4 * 16 + i * 4];
    if (gc0 < 512) {
      const bool isQ = gc0 < 256;
      const int c2 = isQ ? gc0 : gc0 - 256;
      const int head = c2 >> 5, d0 = c2 & 31;
      const float scl = isQ ? QSCALE : 1.f;
      ushort8 hi0, hi1, lo0, lo1;
#pragma unroll
      for (int i = 0; i < 8; ++i) {
        float hf, lf;
        const float sv = v16[i] * scl;
        hi0[i] = bf16_rn(sv, &hf);
        lo0[i] = bf16_rn(sv - hf, &lf);
      }
#pragma unroll
      for (int i = 0; i < 8; ++i) {
        float hf, lf;
        const float sv = v16[8 + i] * scl;
        hi1[i] = bf16_rn(sv, &hf);
        lo1[i] = bf16_rn(sv - hf, &lf);
      }
      unsigned short* dst =
          (isQ ? Q2 : K2) + ((size_t)(bb * 8 + head) * 512 + l) * 64 + d0;
      *(ushort8*)dst = hi0;
      *(ushort8*)(dst + 8) = hi1;
      *(ushort8*)(dst + 32) = lo0;
      *(ushort8*)(dst + 40) = lo1;
    } else if (gc0 < 520) {  // V block: gc0 == 512, cols 512..519
#pragma unroll
      for (int i = 0; i < 8; ++i)
        Vw[(size_t)(bb * 8 + i) * 512 + l] = v16[i];
    }
  }
}

// Block (qhalf, h, b), 512 thr, whole head in LDS, two-pass softmax.
__global__ __launch_bounds__(512) void attn_kernel(
    const unsigned short* __restrict__ Q2, const unsigned short* __restrict__ K2,
    const float* __restrict__ Vw, const int* __restrict__ mask,
    float* __restrict__ vws) {
  __shared__ unsigned short KS[512][72];  // 72 KB
  __shared__ float VwS[512], biasS[512];
  const int t = threadIdx.x;
  const int w = t >> 6, lane = t & 63, g = lane >> 4, r16 = lane & 15;
  const int qbase = blockIdx.x * 256, h = blockIdx.y, b = blockIdx.z;
  const size_t headoff = (size_t)(b * 8 + h) * 512;

#pragma unroll
  for (int i = 0; i < 8; ++i) {
    const int flat = i * 512 + t, row = flat >> 3, cg = (flat & 7) * 8;
    *(ushort8*)&KS[row][cg] = *(const ushort8*)&K2[(headoff + row) * 64 + cg];
  }
  VwS[t] = Vw[headoff + t];
  biasS[t] = mask[b * 512 + t] ? 0.f : NEG * LOG2E;

  bf16x8 qf[2][2];  // [qtile][hi/lo]
#pragma unroll
  for (int qt = 0; qt < 2; ++qt)
#pragma unroll
    for (int ks = 0; ks < 2; ++ks)
      qf[qt][ks] = *(const bf16x8*)
          &Q2[(headoff + qbase + w * 32 + qt * 16 + r16) * 64 + ks * 32 + g * 8];

  __syncthreads();

  // ---- pass 1: max over all 512 keys ----
  float mx[2] = {-3e38f, -3e38f};
  for (int c = 0; c < 8; ++c) {
    bf16x8 a0[4], a1[4];
#pragma unroll
    for (int j = 0; j < 4; ++j) {
      a0[j] = *(const bf16x8*)&KS[c * 64 + j * 16 + r16][g * 8];
      a1[j] = *(const bf16x8*)&KS[c * 64 + j * 16 + r16][32 + g * 8];
    }
#pragma unroll
    for (int qt = 0; qt < 2; ++qt) {
#pragma unroll
      for (int j = 0; j < 4; ++j) {
        f32x4 z = (f32x4){0.f, 0.f, 0.f, 0.f};
        z = __builtin_amdgcn_mfma_f32_16x16x32_bf16(a0[j], qf[qt][0], z, 0, 0, 0);
        z = __builtin_amdgcn_mfma_f32_16x16x32_bf16(a0[j], qf[qt][1], z, 0, 0, 0);
        z = __builtin_amdgcn_mfma_f32_16x16x32_bf16(a1[j], qf[qt][0], z, 0, 0, 0);
        const float4 bsj = *(const float4*)&biasS[c * 64 + j * 16 + g * 4];
        const float m01 = fmaxf(z[0] + bsj.x, z[1] + bsj.y);
        const float m23 = fmaxf(z[2] + bsj.z, z[3] + bsj.w);
        mx[qt] = fmaxf(mx[qt], fmaxf(m01, m23));
      }
    }
  }
#pragma unroll
  for (int qt = 0; qt < 2; ++qt) {
    mx[qt] = fmaxf(mx[qt], __shfl_xor(mx[qt], 16));
    mx[qt] = fmaxf(mx[qt], __shfl_xor(mx[qt], 32));
  }

  // ---- pass 2: exp-sum with known max (no rescale chain) ----
  float ls[2] = {0.f, 0.f}, vv[2] = {0.f, 0.f};
  for (int c = 0; c < 8; ++c) {
    bf16x8 a0[4], a1[4];
#pragma unroll
    for (int j = 0; j < 4; ++j) {
      a0[j] = *(const bf16x8*)&KS[c * 64 + j * 16 + r16][g * 8];
      a1[j] = *(const bf16x8*)&KS[c * 64 + j * 16 + r16][32 + g * 8];
    }
#pragma unroll
    for (int qt = 0; qt < 2; ++qt) {
#pragma unroll
      for (int j = 0; j < 4; ++j) {
        f32x4 z = (f32x4){0.f, 0.f, 0.f, 0.f};
        z = __builtin_amdgcn_mfma_f32_16x16x32_bf16(a0[j], qf[qt][0], z, 0, 0, 0);
        z = __builtin_amdgcn_mfma_f32_16x16x32_bf16(a0[j], qf[qt][1], z, 0, 0, 0);
        z = __builtin_amdgcn_mfma_f32_16x16x32_bf16(a1[j], qf[qt][0], z, 0, 0, 0);
        const float4 bsj = *(const float4*)&biasS[c * 64 + j * 16 + g * 4];
        const float4 vwj = *(const float4*)&VwS[c * 64 + j * 16 + g * 4];
        const float p0 = __builtin_amdgcn_exp2f(z[0] + bsj.x - mx[qt]);
        const float p1 = __builtin_amdgcn_exp2f(z[1] + bsj.y - mx[qt]);
        const float p2 = __builtin_amdgcn_exp2f(z[2] + bsj.z - mx[qt]);
        const float p3 = __builtin_amdgcn_exp2f(z[3] + bsj.w - mx[qt]);
        ls[qt] += (p0 + p1) + (p2 + p3);
        float a = fmaf(p0, vwj.x, vv[qt]);
        a = fmaf(p1, vwj.y, a);
        a = fmaf(p2, vwj.z, a);
        vv[qt] = fmaf(p3, vwj.w, a);
      }
    }
  }
#pragma unroll
  for (int qt = 0; qt < 2; ++qt) {
    ls[qt] += __shfl_xor(ls[qt], 16);
    vv[qt] += __shfl_xor(vv[qt], 16);
    ls[qt] += __shfl_xor(ls[qt], 32);
    vv[qt] += __shfl_xor(vv[qt], 32);
  }
  if (lane < 16) {
#pragma unroll
    for (int qt = 0; qt < 2; ++qt)
      vws[headoff + qbase + w * 32 + qt * 16 + lane] = vv[qt] / ls[qt];
  }
}

__global__ __launch_bounds__(512) void final_kernel(
    const float* __restrict__ vws, const int* __restrict__ mask,
    float* __restrict__ out) {
  const int b = blockIdx.x, l = threadIdx.x;  // grid 32, block 512
  __shared__ float redm[8], reds[8];
  float v = 0.f;
#pragma unroll
  for (int h = 0; h < 8; ++h) v += vws[(size_t)(b * 8 + h) * 512 + l];
  if (mask[b * 512 + l] == 0) v = NEG;
  float mx = v;
#pragma unroll
  for (int off = 32; off >= 1; off >>= 1) mx = fmaxf(mx, __shfl_xor(mx, off));
  if ((l & 63) == 0) redm[l >> 6] = mx;
  __syncthreads();
  float M = redm[0];
#pragma unroll
  for (int i = 1; i < 8; ++i) M = fmaxf(M, redm[i]);
  const float e = __expf(v - M);
  float sm = e;
#pragma unroll
  for (int off = 32; off >= 1; off >>= 1) sm += __shfl_xor(sm, off);
  if ((l & 63) == 0) reds[l >> 6] = sm;
  __syncthreads();
  float S = 0.f;
#pragma unroll
  for (int i = 0; i < 8; ++i) S += reds[i];
  out[b * 512 + l] = e / S;
}

extern "C" void kernel_launch(void* const* d_in, const int* in_sizes, int n_in,
                              void* d_out, int out_size, void* d_ws, size_t ws_size,
                              hipStream_t stream) {
  const float* X  = (const float*)d_in[0];
  const int*  mk  = (const int*)d_in[1];
  const float* W1 = (const float*)d_in[2];
  const float* W2 = (const float*)d_in[3];
  const float* W3 = (const float*)d_in[4];
  const float* w  = (const float*)d_in[5];
  float* out = (float*)d_out;

  char* ws = (char*)d_ws;
  unsigned short* X2 = (unsigned short*)ws;                 // 16384*256  = 8 MB
  unsigned short* Wc = X2 + (size_t)16384 * 256;            //   576*256  = 288 KB
  unsigned short* Q2 = Wc + (size_t)576 * 256;              // 32*8*512*64 = 16 MB
  unsigned short* K2 = Q2 + (size_t)32 * 8 * 512 * 64;      // 16 MB
  float* Vw  = (float*)(K2 + (size_t)32 * 8 * 512 * 64);    // 512 KB
  float* vws = Vw + (size_t)32 * 8 * 512;                   // 512 KB

  convert_kernel<<<dim3(1057), dim3(256), 0, stream>>>(X, W1, W2, W3, w, X2, Wc);
  proj_kernel<<<dim3(9, 256), dim3(256), 0, stream>>>(X2, Wc, Q2, K2, Vw);
  attn_kernel<<<dim3(2, 8, 32), dim3(512), 0, stream>>>(Q2, K2, Vw, mk, vws);
  final_kernel<<<dim3(32), dim3(512), 0, stream>>>(vws, mk, out);
}

// Round 9
// 63.023 us; speedup vs baseline: 1.8304x; 1.1579x over previous
//
#include <hip/hip_runtime.h>
#include <hip/hip_bf16.h>

// AttentionNTKChoiceModel — r9: r4 base + lane-local online softmax attn.
// B=32, L=512, D=128, H=8, D0=D2=32.
//
// convert: X[16384,128]f32 -> X2[16384,256]bf16  (cols 0..127 hi, 128..255 lo)
//          Wc[576,256]bf16: rows W1(0..255), W2(256..511), u(512..519), 0-pad
//          u_h = sum_d w[h,d]*W3[h*32+d,:]/sqrt(8)
// proj:    acc = X2 . Wc[diag chunk] + X2 . Wc[chunk+128 mod 256]
//          (diag = hh+ll, shifted = hl+lh -> exact f32 product). 64x64 tile.
//          Epilogue re-splits into per-head Q2/K2 [B,H,L,64]bf16
//          (d 0..31 hi, 32..63 lo; Q pre-scaled 1/sqrt(32)*log2e), Vw[B,H,L]f32.
// attn:    per (qhalf,h,b): whole 512-key head in LDS (1 barrier).
//          scores^T = K @ Q^T 3-term (hh+hl+lh), bias pre-loaded into the
//          MFMA accumulator. LANE-LOCAL online max/l/v (no cross-lane ops in
//          the loop); split-softmax merge across the 4 lane-groups at the end.
// final:   sum heads, q-mask, 512-wide softmax per batch row.

typedef __attribute__((ext_vector_type(8))) short bf16x8;
typedef __attribute__((ext_vector_type(4))) float f32x4;
typedef __attribute__((ext_vector_type(8))) unsigned short ushort8;
typedef __attribute__((ext_vector_type(4))) unsigned short ushort4v;

#define NEG (-10000.0f)
#define LOG2E 1.4426950408889634f
#define QSCALE (0.17677669529663687f * LOG2E)

__device__ __forceinline__ unsigned short bf16_rn(float x, float* rep) {
  unsigned u = __float_as_uint(x);
  unsigned r = (u + 0x7FFFu + ((u >> 16) & 1u)) >> 16;
  *rep = __uint_as_float(r << 16);
  return (unsigned short)r;
}

// grid 1057 x 256: [0,1024) X-split, [1024,1056) W1/W2-split, 1056 u+pad
__global__ __launch_bounds__(256) void convert_kernel(
    const float* __restrict__ X, const float* __restrict__ W1,
    const float* __restrict__ W2, const float* __restrict__ W3,
    const float* __restrict__ w,
    unsigned short* __restrict__ X2, unsigned short* __restrict__ Wc) {
  const int bx = blockIdx.x, t = threadIdx.x;
  if (bx < 1056) {
    const float* src;
    unsigned short* dst;
    int row, c;
    if (bx < 1024) {
      const size_t flat = (size_t)bx * 2048 + t * 8;
      row = (int)(flat >> 7); c = (int)(flat & 127);
      src = &X[flat];
      dst = &X2[(size_t)row * 256 + c];
    } else {
      const int flat = (bx - 1024) * 2048 + t * 8;
      row = flat >> 7; c = flat & 127;
      src = (row < 256) ? &W1[(size_t)row * 128 + c]
                        : &W2[(size_t)(row - 256) * 128 + c];
      dst = &Wc[(size_t)row * 256 + c];
    }
    float xv[8];
    *(float4*)&xv[0] = *(const float4*)src;
    *(float4*)&xv[4] = *(const float4*)(src + 4);
    ushort8 hi, lo;
#pragma unroll
    for (int i = 0; i < 8; ++i) {
      float hf, lf;
      hi[i] = bf16_rn(xv[i], &hf);
      lo[i] = bf16_rn(xv[i] - hf, &lf);
    }
    *(ushort8*)dst = hi;
    *(ushort8*)(dst + 128) = lo;
  } else {
    __shared__ float uS[8][128];
    if (t < 128) {
#pragma unroll
      for (int h = 0; h < 8; ++h) {
        float acc = 0.f;
#pragma unroll
        for (int d = 0; d < 32; ++d)
          acc += W3[(h * 32 + d) * 128 + t] * w[h * 32 + d];
        uS[h][t] = acc * 0.3535533905932738f;  // 1/sqrt(8)
      }
    }
    __syncthreads();
    {
      const int r = t >> 5, c = (t & 31) * 4;
      float4 v = *(float4*)&uS[r][c];
      float vv[4] = {v.x, v.y, v.z, v.w};
      ushort4v hi, lo;
#pragma unroll
      for (int i = 0; i < 4; ++i) {
        float hf, lf;
        hi[i] = bf16_rn(vv[i], &hf);
        lo[i] = bf16_rn(vv[i] - hf, &lf);
      }
      *(ushort4v*)&Wc[(size_t)(512 + r) * 256 + c] = hi;
      *(ushort4v*)&Wc[(size_t)(512 + r) * 256 + 128 + c] = lo;
    }
    const ushort8 z = {};
    for (int i = t; i < 1792; i += 256)  // zero rows 520..575
      *(ushort8*)&Wc[(size_t)520 * 256 + i * 8] = z;
  }
}

// [16384,576] GEMM, exact 4-term: diag (hh+ll) + shifted (hl+lh).
// Block 256thr (4 waves), tile 64x64, K chunks of 64 over the 256-wide [hi|lo].
__global__ __launch_bounds__(256) void proj_kernel(
    const unsigned short* __restrict__ X2, const unsigned short* __restrict__ Wc,
    unsigned short* __restrict__ Q2, unsigned short* __restrict__ K2,
    float* __restrict__ Vw) {
  // stride 72 ushort = 144B (36 dw, %8==4 -> 2-way max on frag reads)
  __shared__ unsigned short XS[64][72], WSd[64][72], WSx[64][72];
  const int t = threadIdx.x;
  const int row0 = blockIdx.x * 64, col0 = blockIdx.y * 64;
  const int w = t >> 6, lane = t & 63, g = lane >> 4, r16 = lane & 15;
  const int srow = t >> 2, su = (t & 3) * 16;

  f32x4 acc[4];
#pragma unroll
  for (int n = 0; n < 4; ++n) acc[n] = (f32x4){0.f, 0.f, 0.f, 0.f};

  for (int kc = 0; kc < 256; kc += 64) {
    const int kcx = (kc + 128) & 255;
    if (kc) __syncthreads();
    {
      const size_t xo = (size_t)(row0 + srow) * 256 + kc + su;
      const size_t wd = (size_t)(col0 + srow) * 256 + kc + su;
      const size_t wx = (size_t)(col0 + srow) * 256 + kcx + su;
      ushort8 a = *(const ushort8*)&X2[xo];
      ushort8 b = *(const ushort8*)&X2[xo + 8];
      ushort8 c = *(const ushort8*)&Wc[wd];
      ushort8 d = *(const ushort8*)&Wc[wd + 8];
      ushort8 e = *(const ushort8*)&Wc[wx];
      ushort8 f = *(const ushort8*)&Wc[wx + 8];
      *(ushort8*)&XS[srow][su] = a;
      *(ushort8*)&XS[srow][su + 8] = b;
      *(ushort8*)&WSd[srow][su] = c;
      *(ushort8*)&WSd[srow][su + 8] = d;
      *(ushort8*)&WSx[srow][su] = e;
      *(ushort8*)&WSx[srow][su + 8] = f;
    }
    __syncthreads();
#pragma unroll
    for (int ks = 0; ks < 2; ++ks) {
      bf16x8 ah = *(const bf16x8*)&XS[w * 16 + r16][ks * 32 + g * 8];
#pragma unroll
      for (int n = 0; n < 4; ++n) {
        bf16x8 bd = *(const bf16x8*)&WSd[n * 16 + r16][ks * 32 + g * 8];
        bf16x8 bx = *(const bf16x8*)&WSx[n * 16 + r16][ks * 32 + g * 8];
        acc[n] = __builtin_amdgcn_mfma_f32_16x16x32_bf16(ah, bd, acc[n], 0, 0, 0);
        acc[n] = __builtin_amdgcn_mfma_f32_16x16x32_bf16(ah, bx, acc[n], 0, 0, 0);
      }
    }
  }
  // C layout: row = w*16 + g*4 + r, col = col0 + n*16 + r16 (verified r2)
#pragma unroll
  for (int n = 0; n < 4; ++n) {
    const int col = col0 + n * 16 + r16;
#pragma unroll
    for (int r = 0; r < 4; ++r) {
      const int row = row0 + w * 16 + g * 4 + r;
      const int b = row >> 9, l = row & 511;
      const float val = acc[n][r];
      if (col < 256) {
        const float sv = val * QSCALE;
        float hf, lf;
        const unsigned short hb = bf16_rn(sv, &hf);
        const unsigned short lb = bf16_rn(sv - hf, &lf);
        const size_t o = ((size_t)(b * 8 + (col >> 5)) * 512 + l) * 64 + (col & 31);
        Q2[o] = hb; Q2[o + 32] = lb;
      } else if (col < 512) {
        const int c2 = col - 256;
        float hf, lf;
        const unsigned short hb = bf16_rn(val, &hf);
        const unsigned short lb = bf16_rn(val - hf, &lf);
        const size_t o = ((size_t)(b * 8 + (c2 >> 5)) * 512 + l) * 64 + (c2 & 31);
        K2[o] = hb; K2[o + 32] = lb;
      } else if (col < 520) {
        Vw[(size_t)(b * 8 + (col - 512)) * 512 + l] = val;
      }
    }
  }
}

// Block (qhalf, h, b), 512 thr, whole head in LDS (1 barrier).
// Lane-local online softmax: no cross-lane ops until the final merge.
__global__ __launch_bounds__(512, 4) void attn_kernel(
    const unsigned short* __restrict__ Q2, const unsigned short* __restrict__ K2,
    const float* __restrict__ Vw, const int* __restrict__ mask,
    float* __restrict__ vws) {
  __shared__ unsigned short KS[512][72];  // 72 KB
  __shared__ float VwS[512], biasS[512];
  const int t = threadIdx.x;
  const int w = t >> 6, lane = t & 63, g = lane >> 4, r16 = lane & 15;
  const int qbase = blockIdx.x * 256, h = blockIdx.y, b = blockIdx.z;
  const size_t headoff = (size_t)(b * 8 + h) * 512;

#pragma unroll
  for (int i = 0; i < 8; ++i) {
    const int flat = i * 512 + t, row = flat >> 3, cg = (flat & 7) * 8;
    *(ushort8*)&KS[row][cg] = *(const ushort8*)&K2[(headoff + row) * 64 + cg];
  }
  VwS[t] = Vw[headoff + t];
  biasS[t] = mask[b * 512 + t] ? 0.f : NEG * LOG2E;

  bf16x8 qf[2][2];  // [qtile][hi/lo]
#pragma unroll
  for (int qt = 0; qt < 2; ++qt)
#pragma unroll
    for (int ks = 0; ks < 2; ++ks)
      qf[qt][ks] = *(const bf16x8*)
          &Q2[(headoff + qbase + w * 32 + qt * 16 + r16) * 64 + ks * 32 + g * 8];

  __syncthreads();

  // lane-local online state per qtile
  float m[2] = {-3e38f, -3e38f}, ls[2] = {0.f, 0.f}, vv[2] = {0.f, 0.f};

  for (int c = 0; c < 8; ++c) {
    bf16x8 a0[4], a1[4];
#pragma unroll
    for (int j = 0; j < 4; ++j) {
      a0[j] = *(const bf16x8*)&KS[c * 64 + j * 16 + r16][g * 8];
      a1[j] = *(const bf16x8*)&KS[c * 64 + j * 16 + r16][32 + g * 8];
    }
    float4 bs4[4], vw4[4];
#pragma unroll
    for (int j = 0; j < 4; ++j) {
      bs4[j] = *(const float4*)&biasS[c * 64 + j * 16 + g * 4];
      vw4[j] = *(const float4*)&VwS[c * 64 + j * 16 + g * 4];
    }
#pragma unroll
    for (int qt = 0; qt < 2; ++qt) {
      f32x4 sc[4];
#pragma unroll
      for (int j = 0; j < 4; ++j) {
        f32x4 z = (f32x4){bs4[j].x, bs4[j].y, bs4[j].z, bs4[j].w};  // bias in C
        z = __builtin_amdgcn_mfma_f32_16x16x32_bf16(a0[j], qf[qt][0], z, 0, 0, 0);
        z = __builtin_amdgcn_mfma_f32_16x16x32_bf16(a0[j], qf[qt][1], z, 0, 0, 0);
        z = __builtin_amdgcn_mfma_f32_16x16x32_bf16(a1[j], qf[qt][0], z, 0, 0, 0);
        sc[j] = z;
      }
      // lane-local max of the 16 scores
      float cm01 = fmaxf(fmaxf(sc[0][0], sc[0][1]), fmaxf(sc[0][2], sc[0][3]));
      float cm23 = fmaxf(fmaxf(sc[1][0], sc[1][1]), fmaxf(sc[1][2], sc[1][3]));
      float cm45 = fmaxf(fmaxf(sc[2][0], sc[2][1]), fmaxf(sc[2][2], sc[2][3]));
      float cm67 = fmaxf(fmaxf(sc[3][0], sc[3][1]), fmaxf(sc[3][2], sc[3][3]));
      const float cmax = fmaxf(fmaxf(cm01, cm23), fmaxf(cm45, cm67));
      const float mnew = fmaxf(m[qt], cmax);
      const float f = __builtin_amdgcn_exp2f(m[qt] - mnew);
      m[qt] = mnew;
      float l = ls[qt] * f, v = vv[qt] * f;
#pragma unroll
      for (int j = 0; j < 4; ++j) {
        const float p0 = __builtin_amdgcn_exp2f(sc[j][0] - mnew);
        const float p1 = __builtin_amdgcn_exp2f(sc[j][1] - mnew);
        const float p2 = __builtin_amdgcn_exp2f(sc[j][2] - mnew);
        const float p3 = __builtin_amdgcn_exp2f(sc[j][3] - mnew);
        l += (p0 + p1) + (p2 + p3);
        v = fmaf(p0, vw4[j].x, v);
        v = fmaf(p1, vw4[j].y, v);
        v = fmaf(p2, vw4[j].z, v);
        v = fmaf(p3, vw4[j].w, v);
      }
      ls[qt] = l; vv[qt] = v;
    }
  }
  // split-softmax merge across the 4 lane groups (xor 16, then 32)
#pragma unroll
  for (int qt = 0; qt < 2; ++qt) {
#pragma unroll
    for (int off = 16; off <= 32; off <<= 1) {
      const float mo = __shfl_xor(m[qt], off);
      const float lo_ = __shfl_xor(ls[qt], off);
      const float vo = __shfl_xor(vv[qt], off);
      const float m2 = fmaxf(m[qt], mo);
      const float fa = __builtin_amdgcn_exp2f(m[qt] - m2);
      const float fb = __builtin_amdgcn_exp2f(mo - m2);
      ls[qt] = ls[qt] * fa + lo_ * fb;
      vv[qt] = vv[qt] * fa + vo * fb;
      m[qt] = m2;
    }
  }
  if (lane < 16) {
#pragma unroll
    for (int qt = 0; qt < 2; ++qt)
      vws[headoff + qbase + w * 32 + qt * 16 + lane] = vv[qt] / ls[qt];
  }
}

__global__ __launch_bounds__(512) void final_kernel(
    const float* __restrict__ vws, const int* __restrict__ mask,
    float* __restrict__ out) {
  const int b = blockIdx.x, l = threadIdx.x;  // grid 32, block 512
  __shared__ float redm[8], reds[8];
  float v = 0.f;
#pragma unroll
  for (int h = 0; h < 8; ++h) v += vws[(size_t)(b * 8 + h) * 512 + l];
  if (mask[b * 512 + l] == 0) v = NEG;
  float mx = v;
#pragma unroll
  for (int off = 32; off >= 1; off >>= 1) mx = fmaxf(mx, __shfl_xor(mx, off));
  if ((l & 63) == 0) redm[l >> 6] = mx;
  __syncthreads();
  float M = redm[0];
#pragma unroll
  for (int i = 1; i < 8; ++i) M = fmaxf(M, redm[i]);
  const float e = __expf(v - M);
  float sm = e;
#pragma unroll
  for (int off = 32; off >= 1; off >>= 1) sm += __shfl_xor(sm, off);
  if ((l & 63) == 0) reds[l >> 6] = sm;
  __syncthreads();
  float S = 0.f;
#pragma unroll
  for (int i = 0; i < 8; ++i) S += reds[i];
  out[b * 512 + l] = e / S;
}

extern "C" void kernel_launch(void* const* d_in, const int* in_sizes, int n_in,
                              void* d_out, int out_size, void* d_ws, size_t ws_size,
                              hipStream_t stream) {
  const float* X  = (const float*)d_in[0];
  const int*  mk  = (const int*)d_in[1];
  const float* W1 = (const float*)d_in[2];
  const float* W2 = (const float*)d_in[3];
  const float* W3 = (const float*)d_in[4];
  const float* w  = (const float*)d_in[5];
  float* out = (float*)d_out;

  char* ws = (char*)d_ws;
  unsigned short* X2 = (unsigned short*)ws;                 // 16384*256  = 8 MB
  unsigned short* Wc = X2 + (size_t)16384 * 256;            //   576*256  = 288 KB
  unsigned short* Q2 = Wc + (size_t)576 * 256;              // 32*8*512*64 = 16 MB
  unsigned short* K2 = Q2 + (size_t)32 * 8 * 512 * 64;      // 16 MB
  float* Vw  = (float*)(K2 + (size_t)32 * 8 * 512 * 64);    // 512 KB
  float* vws = Vw + (size_t)32 * 8 * 512;                   // 512 KB

  convert_kernel<<<dim3(1057), dim3(256), 0, stream>>>(X, W1, W2, W3, w, X2, Wc);
  proj_kernel<<<dim3(256, 9), dim3(256), 0, stream>>>(X2, Wc, Q2, K2, Vw);
  attn_kernel<<<dim3(2, 8, 32), dim3(512), 0, stream>>>(Q2, K2, Vw, mk, vws);
  final_kernel<<<dim3(32), dim3(512), 0, stream>>>(vws, mk, out);
}